// Round 10
// baseline (23.510 us; speedup 1.0000x reference)
//
#include <hip/hip_runtime.h>
#include <math.h>

// DETR HungarianMatcher cost matrix on MI355X — round 10 (R9 + splat fix).
// cost[n,m] = 0.3125*cb_s + (2-prob) - 2*(inter/uni + uni/ae)  with all box
// geometry scaled x16 (exact pow2) and processed 2 targets/op via native
// _Float16 ext-vectors (v_pk_*_f16). ROWS=8, 2000 blocks,
// launch_bounds(256,7), software-pipelined row loop, nontemporal stores.

#define NROWS 16000
#define NC 92
#define M_TGT 1024
#define TPB 256
#define ROWS 8

typedef float f32x4 __attribute__((ext_vector_type(4)));
typedef _Float16 h2 __attribute__((ext_vector_type(2)));

__device__ __forceinline__ h2 h2_rcp(h2 x) {
    h2 r;
    r.x = __builtin_amdgcn_rcph(x.x);
    r.y = __builtin_amdgcn_rcph(x.y);
    return r;
}

__device__ __forceinline__ h2 h2_splat(float v) {
    const _Float16 h = (_Float16)v;
    return h2{h, h};
}

__global__ __launch_bounds__(TPB, 7) void hungarian_cost_kernel(
    const float* __restrict__ logits,   // [NROWS, NC]
    const float* __restrict__ pboxes,   // [NROWS, 4] cxcywh
    const float* __restrict__ tboxes,   // [M_TGT, 4] cxcywh
    const int*   __restrict__ tlabels,  // [M_TGT]
    float* __restrict__ out)            // [NROWS, M_TGT]
{
    const int n0 = blockIdx.x * ROWS;
    const int t = threadIdx.x;
    const int lane = t & 63;
    const int wid  = t >> 6;

    __shared__ _Float16 negp[ROWS][96];   // 2 - softmax prob (f16)

    // ---- softmax: wave `wid` handles rows 2*wid, 2*wid+1 ----
    #pragma unroll
    for (int j = 0; j < 2; ++j) {
        const int r = wid * 2 + j;
        const float* lg = logits + (size_t)(n0 + r) * NC;
        const float x0 = lg[lane];                 // lanes 0..63
        const bool  hi = (lane < NC - 64);         // lanes 0..27 cover 64..91
        const float x1 = hi ? lg[64 + lane] : -INFINITY;
        float mx = fmaxf(x0, x1);
        #pragma unroll
        for (int off = 32; off >= 1; off >>= 1)
            mx = fmaxf(mx, __shfl_xor(mx, off));
        const float e0 = __expf(x0 - mx);
        const float e1 = hi ? __expf(x1 - mx) : 0.0f;
        float s = e0 + e1;
        #pragma unroll
        for (int off = 32; off >= 1; off >>= 1)
            s += __shfl_xor(s, off);
        const float rs = __builtin_amdgcn_rcpf(s);
        negp[r][lane] = (_Float16)fmaf(-e0, rs, 2.0f);
        if (hi) negp[r][64 + lane] = (_Float16)fmaf(-e1, rs, 2.0f);
    }

    // ---- per-thread target context: 2 h2 pairs (targets 4t..4t+3), x16 ----
    h2 tcx2[2], tcy2[2], twd2[2], tht2[2];
    h2 bx02[2], by02[2], bx12[2], by12[2], areab2[2];
    int lblA[2], lblB[2];
    {
        const int4 lb4 = reinterpret_cast<const int4*>(tlabels)[t];
        int l[4] = {lb4.x, lb4.y, lb4.z, lb4.w};
        #pragma unroll
        for (int k = 0; k < 4; ++k)
            l[k] = (l[k] < 0) ? 0 : (l[k] > NC - 1 ? NC - 1 : l[k]);
        lblA[0] = l[0]; lblB[0] = l[1]; lblA[1] = l[2]; lblB[1] = l[3];
        #pragma unroll
        for (int p = 0; p < 2; ++p) {
            const float4 A = reinterpret_cast<const float4*>(tboxes)[4 * t + 2 * p];
            const float4 B = reinterpret_cast<const float4*>(tboxes)[4 * t + 2 * p + 1];
            const float Ax = A.x * 16.0f, Ay = A.y * 16.0f, Aw = A.z * 16.0f, Ah = A.w * 16.0f;
            const float Bx = B.x * 16.0f, By = B.y * 16.0f, Bw = B.z * 16.0f, Bh = B.w * 16.0f;
            tcx2[p] = h2{(_Float16)Ax, (_Float16)Bx};
            tcy2[p] = h2{(_Float16)Ay, (_Float16)By};
            twd2[p] = h2{(_Float16)Aw, (_Float16)Bw};
            tht2[p] = h2{(_Float16)Ah, (_Float16)Bh};
            bx02[p] = h2{(_Float16)fmaf(-0.5f, Aw, Ax), (_Float16)fmaf(-0.5f, Bw, Bx)};
            by02[p] = h2{(_Float16)fmaf(-0.5f, Ah, Ay), (_Float16)fmaf(-0.5f, Bh, By)};
            bx12[p] = h2{(_Float16)fmaf( 0.5f, Aw, Ax), (_Float16)fmaf( 0.5f, Bw, Bx)};
            by12[p] = h2{(_Float16)fmaf( 0.5f, Ah, Ay), (_Float16)fmaf( 0.5f, Bh, By)};
            areab2[p] = h2{(_Float16)(Aw * Ah), (_Float16)(Bw * Bh)};
        }
    }
    __syncthreads();

    const h2 kz   = h2_splat(0.0f);
    const h2 keps = h2_splat(1.0e-4f);
    const _Float16 k3125 = (_Float16)0.3125f;   // 5/16
    const _Float16 km2   = (_Float16)-2.0f;

    // ---- software-pipelined main loop over 8 rows ----
    float4 pb = reinterpret_cast<const float4*>(pboxes)[n0];   // uniform
    h2 cls2[2];
    #pragma unroll
    for (int p = 0; p < 2; ++p)
        cls2[p] = h2{negp[0][lblA[p]], negp[0][lblB[p]]};

    #pragma unroll
    for (int r = 0; r < ROWS; ++r) {
        // prefetch next row's gathers + pred box
        h2 cls2N[2];
        float4 pbN;
        if (r + 1 < ROWS) {
            #pragma unroll
            for (int p = 0; p < 2; ++p)
                cls2N[p] = h2{negp[r + 1][lblA[p]], negp[r + 1][lblB[p]]};
            pbN = reinterpret_cast<const float4*>(pboxes)[n0 + r + 1];
        }

        // per-row context (scaled x16, splat to h2)
        const float sx = pb.x * 16.0f, sy = pb.y * 16.0f;
        const float sw = pb.z * 16.0f, sh = pb.w * 16.0f;
        const h2 px2 = h2_splat(sx), py2 = h2_splat(sy);
        const h2 pw2 = h2_splat(sw), ph2 = h2_splat(sh);
        const h2 ax02 = h2_splat(fmaf(-0.5f, sw, sx));
        const h2 ay02 = h2_splat(fmaf(-0.5f, sh, sy));
        const h2 ax12 = h2_splat(fmaf( 0.5f, sw, sx));
        const h2 ay12 = h2_splat(fmaf( 0.5f, sh, sy));
        const h2 area_a2 = h2_splat(sw * sh);

        float tmpf[4];
        #pragma unroll
        for (int p = 0; p < 2; ++p) {
            const h2 dx = __builtin_elementwise_abs(px2 - tcx2[p]);
            const h2 dy = __builtin_elementwise_abs(py2 - tcy2[p]);
            const h2 dw = __builtin_elementwise_abs(pw2 - twd2[p]);
            const h2 dh = __builtin_elementwise_abs(ph2 - tht2[p]);
            const h2 cb2 = (dx + dy) + (dw + dh);

            const h2 iwu = __builtin_elementwise_min(ax12, bx12[p])
                         - __builtin_elementwise_max(ax02, bx02[p]);
            const h2 ihu = __builtin_elementwise_min(ay12, by12[p])
                         - __builtin_elementwise_max(ay02, by02[p]);
            const h2 inter = __builtin_elementwise_max(iwu, kz)
                           * __builtin_elementwise_max(ihu, kz);
            const h2 uni = (area_a2 + areab2[p]) - inter;
            const h2 ew = (pw2 + twd2[p]) - iwu;   // max(a1,b1)-min(a0,b0)
            const h2 eh = (ph2 + tht2[p]) - ihu;
            const h2 ae = ew * eh;

            const h2 runi = h2_rcp(__builtin_elementwise_max(uni, keps));
            const h2 rae  = h2_rcp(__builtin_elementwise_max(ae, keps));
            const h2 hv = inter * runi + uni * rae;
            const h2 cost2 = k3125 * cb2 + (km2 * hv + cls2[p]);

            tmpf[2 * p]     = (float)cost2.x;
            tmpf[2 * p + 1] = (float)cost2.y;
        }

        f32x4 res = {tmpf[0], tmpf[1], tmpf[2], tmpf[3]};
        __builtin_nontemporal_store(res,
            reinterpret_cast<f32x4*>(out + ((size_t)(n0 + r) << 10)) + t);

        cls2[0] = cls2N[0]; cls2[1] = cls2N[1];
        pb = pbN;
    }
}

extern "C" void kernel_launch(void* const* d_in, const int* in_sizes, int n_in,
                              void* d_out, int out_size, void* d_ws, size_t ws_size,
                              hipStream_t stream) {
    const float* logits  = (const float*)d_in[0];  // [16,1000,92]
    const float* pboxes  = (const float*)d_in[1];  // [16,1000,4]
    const float* tboxes  = (const float*)d_in[2];  // [1024,4]
    const int*   tlabels = (const int*)d_in[3];    // [1024]
    float* out = (float*)d_out;                    // [16,1000,1024]

    hungarian_cost_kernel<<<NROWS / ROWS, TPB, 0, stream>>>(
        logits, pboxes, tboxes, tlabels, out);
}